// Round 8
// baseline (413.199 us; speedup 1.0000x reference)
//
#include <hip/hip_runtime.h>
#include <hip/hip_bf16.h>

typedef __hip_bfloat16 bf16;
typedef __attribute__((ext_vector_type(8))) short bf16x8;  // 8 bf16 in 4 VGPRs
typedef __attribute__((ext_vector_type(4))) float f32x4;

__device__ inline float bf2f(bf16 v) { return __bfloat162float(v); }
__device__ inline bf16 f2bf(float f) { return __float2bfloat16(f); }

#define TM 64
#define TN 64
#define BK 32

// GEMM: out[M,N] = A@W + bias.
// A: [M,K] fp32 (AF32) or bf16. W: [K,N] fp32. bias: fp32.
// OUTF32: store fp32 (final projection) vs bf16 (intermediates).
template <bool AF32, bool OUTF32>
__global__ __launch_bounds__(256) void gemm_k(
    const void* __restrict__ Av, const float* __restrict__ W,
    const float* __restrict__ bias, int M, int N, int K,
    void* __restrict__ outv)
{
    __shared__ __align__(16) bf16 lds_a[TM][BK + 8];
    __shared__ __align__(16) bf16 lds_b[TN][BK + 8];  // [n][k]

    const int tid  = threadIdx.x;
    const int wave = tid >> 6, lane = tid & 63;
    const int quad = lane >> 4, l16 = lane & 15;
    const int row0 = blockIdx.x * TM;
    const int n0   = blockIdx.y * TN;

    f32x4 acc[4] = {};

    const int am = tid >> 2, akc = (tid & 3) * 8;   // A staging: 64 rows x 4 chunks of 8
    const int bk = tid >> 3, bnc = (tid & 7) * 8;   // W staging: 32 k x 8 chunks of 8

    for (int k0 = 0; k0 < K; k0 += BK) {
        __syncthreads();
        union { bf16x8 v; bf16 e[8]; } ua;
        if (AF32) {
            const float* A = (const float*)Av;
            const float* p = A + (size_t)(row0 + am) * K + k0 + akc;
            float4 f0 = *(const float4*)(p);
            float4 f1 = *(const float4*)(p + 4);
            ua.e[0] = f2bf(f0.x); ua.e[1] = f2bf(f0.y);
            ua.e[2] = f2bf(f0.z); ua.e[3] = f2bf(f0.w);
            ua.e[4] = f2bf(f1.x); ua.e[5] = f2bf(f1.y);
            ua.e[6] = f2bf(f1.z); ua.e[7] = f2bf(f1.w);
        } else {
            const bf16* A = (const bf16*)Av;
            ua.v = *(const bf16x8*)(A + (size_t)(row0 + am) * K + k0 + akc);
        }
        *(bf16x8*)(&lds_a[am][akc]) = ua.v;
        {
            const float* p = W + (size_t)(k0 + bk) * N + n0 + bnc;
            float4 f0 = *(const float4*)(p);
            float4 f1 = *(const float4*)(p + 4);
            lds_b[bnc + 0][bk] = f2bf(f0.x); lds_b[bnc + 1][bk] = f2bf(f0.y);
            lds_b[bnc + 2][bk] = f2bf(f0.z); lds_b[bnc + 3][bk] = f2bf(f0.w);
            lds_b[bnc + 4][bk] = f2bf(f1.x); lds_b[bnc + 5][bk] = f2bf(f1.y);
            lds_b[bnc + 6][bk] = f2bf(f1.z); lds_b[bnc + 7][bk] = f2bf(f1.w);
        }
        __syncthreads();

        bf16x8 af = *(const bf16x8*)(&lds_a[wave * 16 + l16][quad * 8]);
#pragma unroll
        for (int nt = 0; nt < 4; ++nt) {
            bf16x8 bfg = *(const bf16x8*)(&lds_b[nt * 16 + l16][quad * 8]);
            acc[nt] = __builtin_amdgcn_mfma_f32_16x16x32_bf16(af, bfg, acc[nt], 0, 0, 0);
        }
    }

#pragma unroll
    for (int nt = 0; nt < 4; ++nt) {
        int n = n0 + nt * 16 + l16;
        float bvv = bias[n];
#pragma unroll
        for (int r = 0; r < 4; ++r) {
            int row = row0 + wave * 16 + quad * 4 + r;
            float v = acc[nt][r] + bvv;
            if (OUTF32) ((float*)outv)[(size_t)row * N + n] = v;
            else        ((bf16*)outv)[(size_t)row * N + n] = f2bf(v);
        }
    }
}

// Elementwise RoPE + head scatter. qkv:[4096][3072] bf16 ->
// q/k/v [B,H,T,D] bf16; q pre-scaled by 0.125.
__global__ __launch_bounds__(256) void rope_k(
    const bf16* __restrict__ qkv,
    bf16* __restrict__ q, bf16* __restrict__ k, bf16* __restrict__ v)
{
    int gid = blockIdx.x * 256 + threadIdx.x;   // [0, 2^21)
    int p  = gid & 31, d0 = p * 2;
    int t  = (gid >> 5) & 2047;
    int h  = (gid >> 16) & 15;
    int b  = gid >> 20;

    size_t src = ((size_t)(b * 2048 + t)) * 3072 + h * 64 + d0;
    size_t dst = (((size_t)(b * 16 + h)) * 2048 + t) * 64 + d0;

    float invf = expf(-(float)d0 * (9.210340371976184f / 64.0f));
    float sn, cs;
    sincosf((float)t * invf, &sn, &cs);

    float q0 = bf2f(qkv[src]),        q1 = bf2f(qkv[src + 1]);
    float k0 = bf2f(qkv[src + 1024]), k1 = bf2f(qkv[src + 1025]);
    q[dst]     = f2bf((q0 * cs - q1 * sn) * 0.125f);
    q[dst + 1] = f2bf((q1 * cs + q0 * sn) * 0.125f);
    k[dst]     = f2bf(k0 * cs - k1 * sn);
    k[dst + 1] = f2bf(k1 * cs + k0 * sn);
    v[dst]     = qkv[src + 2048];
    v[dst + 1] = qkv[src + 2049];
}

// Flash attention, causal, MFMA. Q,K,V: [B*H][2048][64] bf16 (q pre-scaled).
// y: [B,T,H*D] bf16. Block: 256 thr = 4 waves x 16 q-rows = 64 q rows.
__global__ __launch_bounds__(256) void attn_k(
    const bf16* __restrict__ qws, const bf16* __restrict__ kws,
    const bf16* __restrict__ vws, bf16* __restrict__ y)
{
    __shared__ __align__(16) bf16 vT[64][72];       // [d][key]
    __shared__ __align__(16) bf16 pL[4][16][72];    // per-wave P  [qrow][key]

    const int tid  = threadIdx.x;
    const int wave = tid >> 6, lane = tid & 63;
    const int quad = lane >> 4, l16 = lane & 15;
    const int qb = blockIdx.x * 64;
    const int bh = blockIdx.y;
    const bf16* Q = qws + (size_t)bh * 2048 * 64;
    const bf16* K = kws + (size_t)bh * 2048 * 64;
    const bf16* V = vws + (size_t)bh * 2048 * 64;
    const int q0 = qb + wave * 16;

    bf16x8 aq[2];
    aq[0] = *(const bf16x8*)(Q + (size_t)(q0 + l16) * 64 + quad * 8);
    aq[1] = *(const bf16x8*)(Q + (size_t)(q0 + l16) * 64 + 32 + quad * 8);

    f32x4 o[4] = {};
    float m_r[4] = {-1e30f, -1e30f, -1e30f, -1e30f};
    float l_r[4] = {0.f, 0.f, 0.f, 0.f};

    const int vkey = tid >> 2, vdc = (tid & 3) * 16;

    for (int kt = 0; kt < qb + 64; kt += 64) {
        __syncthreads();
        bf16x8 v0 = *(const bf16x8*)(V + (size_t)(kt + vkey) * 64 + vdc);
        bf16x8 v1 = *(const bf16x8*)(V + (size_t)(kt + vkey) * 64 + vdc + 8);
#pragma unroll
        for (int i = 0; i < 8; ++i) vT[vdc + i][vkey] = ((const bf16*)&v0)[i];
#pragma unroll
        for (int i = 0; i < 8; ++i) vT[vdc + 8 + i][vkey] = ((const bf16*)&v1)[i];
        __syncthreads();

        f32x4 sc[4] = {};
#pragma unroll
        for (int s = 0; s < 2; ++s) {
#pragma unroll
            for (int nt = 0; nt < 4; ++nt) {
                bf16x8 bk = *(const bf16x8*)(K + (size_t)(kt + nt * 16 + l16) * 64 + s * 32 + quad * 8);
                sc[nt] = __builtin_amdgcn_mfma_f32_16x16x32_bf16(aq[s], bk, sc[nt], 0, 0, 0);
            }
        }

        float rowmax[4] = {-1e30f, -1e30f, -1e30f, -1e30f};
#pragma unroll
        for (int nt = 0; nt < 4; ++nt) {
            int kk = kt + nt * 16 + l16;
#pragma unroll
            for (int r = 0; r < 4; ++r) {
                int qq = q0 + quad * 4 + r;
                float sv = (kk <= qq) ? sc[nt][r] : -1e30f;
                sc[nt][r] = sv;
                rowmax[r] = fmaxf(rowmax[r], sv);
            }
        }
#pragma unroll
        for (int off = 1; off < 16; off <<= 1)
#pragma unroll
            for (int r = 0; r < 4; ++r)
                rowmax[r] = fmaxf(rowmax[r], __shfl_xor(rowmax[r], off));

        float alpha[4];
#pragma unroll
        for (int r = 0; r < 4; ++r) {
            float mn = fmaxf(m_r[r], rowmax[r]);
            alpha[r] = __expf(m_r[r] - mn);
            m_r[r] = mn;
        }
        float rs[4] = {0.f, 0.f, 0.f, 0.f};
#pragma unroll
        for (int nt = 0; nt < 4; ++nt)
#pragma unroll
            for (int r = 0; r < 4; ++r) {
                float p = __expf(sc[nt][r] - m_r[r]);
                sc[nt][r] = p;
                rs[r] += p;
            }
#pragma unroll
        for (int off = 1; off < 16; off <<= 1)
#pragma unroll
            for (int r = 0; r < 4; ++r) rs[r] += __shfl_xor(rs[r], off);
#pragma unroll
        for (int r = 0; r < 4; ++r) l_r[r] = l_r[r] * alpha[r] + rs[r];
#pragma unroll
        for (int nt = 0; nt < 4; ++nt)
#pragma unroll
            for (int r = 0; r < 4; ++r) o[nt][r] *= alpha[r];

        // P -> LDS (C layout), read back as A-operand fragments
#pragma unroll
        for (int nt = 0; nt < 4; ++nt)
#pragma unroll
            for (int r = 0; r < 4; ++r)
                pL[wave][quad * 4 + r][nt * 16 + l16] = f2bf(sc[nt][r]);
        __syncthreads();

#pragma unroll
        for (int s = 0; s < 2; ++s) {
            bf16x8 pa = *(const bf16x8*)(&pL[wave][l16][s * 32 + quad * 8]);
#pragma unroll
            for (int nt = 0; nt < 4; ++nt) {
                bf16x8 vb = *(const bf16x8*)(&vT[nt * 16 + l16][s * 32 + quad * 8]);
                o[nt] = __builtin_amdgcn_mfma_f32_16x16x32_bf16(pa, vb, o[nt], 0, 0, 0);
            }
        }
    }

    const int b = bh >> 4, h = bh & 15;
#pragma unroll
    for (int r = 0; r < 4; ++r) {
        float inv = 1.0f / l_r[r];
        int qq = q0 + quad * 4 + r;
#pragma unroll
        for (int nt = 0; nt < 4; ++nt) {
            int d = nt * 16 + l16;
            y[((size_t)(b * 2048 + qq)) * 1024 + h * 64 + d] = f2bf(o[nt][r] * inv);
        }
    }
}

extern "C" void kernel_launch(void* const* d_in, const int* in_sizes, int n_in,
                              void* d_out, int out_size, void* d_ws, size_t ws_size,
                              hipStream_t stream) {
    const float* x      = (const float*)d_in[0];
    const float* w_attn = (const float*)d_in[1];
    const float* b_attn = (const float*)d_in[2];
    const float* w_proj = (const float*)d_in[3];
    const float* b_proj = (const float*)d_in[4];
    float* out = (float*)d_out;                      // fp32 OUTPUT (reference dtype)

    // ws (bf16 elems): qkv 12.58M | q 4.19M | k 4.19M | v 4.19M ; y reuses qkv
    bf16* qkvws = (bf16*)d_ws;                       // [4096][3072]
    bf16* qws = qkvws + (size_t)4096 * 3072;         // [B,H,T,D]
    bf16* kws = qws + (size_t)4194304;
    bf16* vws = kws + (size_t)4194304;
    bf16* yws = qkvws;                               // reuse (qkv dead after rope_k)

    dim3 blk(256);
    // 1) QKV projection (fp32 A/W -> bf16 out)
    gemm_k<true, false><<<dim3(64, 48), blk, 0, stream>>>(x, w_attn, b_attn,
                                                          4096, 3072, 1024, qkvws);
    // 2) RoPE + 0.125 q-scale + head scatter
    rope_k<<<dim3(8192), blk, 0, stream>>>(qkvws, qws, kws, vws);
    // 3) causal flash attention (MFMA)
    attn_k<<<dim3(32, 32), blk, 0, stream>>>(qws, kws, vws, yws);
    // 4) output projection -> fp32 d_out
    gemm_k<false, true><<<dim3(64, 16), blk, 0, stream>>>(yws, w_proj, b_proj,
                                                          4096, 1024, 1024, out);
    (void)in_sizes; (void)n_in; (void)ws_size; (void)out_size;
}